// Round 2
// baseline (471.047 us; speedup 1.0000x reference)
//
#include <hip/hip_runtime.h>

#define NE 800000
#define D  64
#define K1 192

typedef __bf16 bf16x8 __attribute__((ext_vector_type(8)));
typedef float  f32x4  __attribute__((ext_vector_type(4)));

// Convert W1 (192x64, k-major) -> W1^T bf16 (64x192, n-major) at ws[0],
// and W2 (64x64) -> W2^T bf16 (64x64) at ws[12288]. 16384 threads total.
__global__ void prep_weights(const float* __restrict__ W1,
                             const float* __restrict__ W2,
                             __bf16* __restrict__ ws) {
  int i = blockIdx.x * 256 + threadIdx.x;
  if (i < K1 * D) {
    int k = i >> 6, n = i & 63;
    ws[n * K1 + k] = (__bf16)W1[i];
  } else {
    int j = i - K1 * D;
    int k = j >> 6, n = j & 63;
    ws[K1 * D + n * D + k] = (__bf16)W2[j];
  }
}

// Intra-wave LDS ordering: hbuf is per-wave, so a full block barrier is not
// needed between the h1 write (layer-1 epilogue) and the h1 read (layer-2 A
// fragment). s_waitcnt lgkmcnt(0) + compiler memory fence is sufficient:
// LDS ops from one wave complete in order past the waitcnt.
__device__ __forceinline__ void wave_lds_fence() {
  __asm__ volatile("s_waitcnt lgkmcnt(0)" ::: "memory");
}

template <bool USE_WS>
__global__ __launch_bounds__(256, 4)
void edge_kernel(const float* __restrict__ nodes, const float* __restrict__ ef,
                 const int* __restrict__ srci, const int* __restrict__ dsti,
                 const float* __restrict__ W1, const float* __restrict__ b1,
                 const float* __restrict__ W2, const float* __restrict__ b2,
                 const float* __restrict__ gmm, const float* __restrict__ bta,
                 const __bf16* __restrict__ wsw, float* __restrict__ out) {
  // w1t stride 200 bf16 -> row step = 4 dwords in bank space -> free 2-way
  // conflicts on ds_read_b128 (stride 192 would be 16-way).
  // LDS total: 25600 + 9216 + 1024 = 35840 B -> 4 blocks/CU (<= 40960).
  __shared__ __align__(16) __bf16 w1t[64 * 200];
  __shared__ __align__(16) __bf16 hbuf[4][16 * 72];
  __shared__ float sb1[64], sb2[64], sg[64], sbt[64];

  const int tid = threadIdx.x;
  const int wave = tid >> 6, lane = tid & 63;
  const int quad = lane >> 4, m16 = lane & 15;

  if (USE_WS) {
    const uint2* s1 = (const uint2*)wsw;          // 3072 x 8B chunks
    for (int c = tid; c < 3072; c += 256) {
      int n = c / 48, kc = c - n * 48;
      *(uint2*)&w1t[n * 200 + kc * 4] = s1[c];
    }
  } else {
    for (int i = tid; i < K1 * D; i += 256) {
      int k = i >> 6, n = i & 63;
      w1t[n * 200 + k] = (__bf16)W1[i];
    }
  }
  if (tid < 64)       sb1[tid]       = b1[tid];
  else if (tid < 128) sb2[tid - 64]  = b2[tid - 64];
  else if (tid < 192) sg[tid - 128]  = gmm[tid - 128];
  else                sbt[tid - 192] = bta[tid - 192];

  // W2^T B-fragments live in registers (loop-invariant): 8 x bf16x8 = 32 VGPR.
  bf16x8 w2f[2][4];
  if (USE_WS) {
    const __bf16* w2t = wsw + K1 * D;  // 64x64, n-major
    #pragma unroll
    for (int ki = 0; ki < 2; ++ki)
      #pragma unroll
      for (int nt = 0; nt < 4; ++nt)
        w2f[ki][nt] = *(const bf16x8*)&w2t[(nt * 16 + m16) * 64 + ki * 32 + quad * 8];
  } else {
    #pragma unroll
    for (int ki = 0; ki < 2; ++ki)
      #pragma unroll
      for (int nt = 0; nt < 4; ++nt) {
        const int n = nt * 16 + m16;
        #pragma unroll
        for (int j = 0; j < 8; ++j)
          w2f[ki][nt][j] = (__bf16)W2[(ki * 32 + quad * 8 + j) * 64 + n];
      }
  }
  __syncthreads();  // once: w1t + bias staging visible to all waves

  __bf16* hw = hbuf[wave];

  #pragma unroll 1
  for (int t = 0; t < 4; ++t) {
    const int base = blockIdx.x * 256 + wave * 64 + t * 16;
    const int eRow = base + m16;
    const int s = srci[eRow], d = dsti[eRow];
    const float* r0 = nodes + (size_t)s * D;
    const float* r1 = nodes + (size_t)d * D;
    const float* r2 = ef + (size_t)eRow * D;

    // ---- layer 1: [16 x 192] @ [192 x 64] ----
    f32x4 acc[4] = {};
    #pragma unroll
    for (int ki = 0; ki < 6; ++ki) {
      // lane's 8 k's (quad*8..+8 within this 32-k step) fall entirely in one
      // of the three concat sources
      const float* p;
      if (ki < 2)      p = r0 + ki * 32 + quad * 8;
      else if (ki < 4) p = r1 + (ki - 2) * 32 + quad * 8;
      else             p = r2 + (ki - 4) * 32 + quad * 8;
      f32x4 lo = *(const f32x4*)p;
      f32x4 hi = *(const f32x4*)(p + 4);
      bf16x8 a;
      a[0] = (__bf16)lo[0]; a[1] = (__bf16)lo[1];
      a[2] = (__bf16)lo[2]; a[3] = (__bf16)lo[3];
      a[4] = (__bf16)hi[0]; a[5] = (__bf16)hi[1];
      a[6] = (__bf16)hi[2]; a[7] = (__bf16)hi[3];
      const int wk = ki * 32 + quad * 8;
      #pragma unroll
      for (int nt = 0; nt < 4; ++nt) {
        bf16x8 bf = *(const bf16x8*)&w1t[(nt * 16 + m16) * 200 + wk];
        acc[nt] = __builtin_amdgcn_mfma_f32_16x16x32_bf16(a, bf, acc[nt], 0, 0, 0);
      }
    }

    // bias + SiLU (fp32), write h1 to LDS in [row][col] for A-layout re-read
    #pragma unroll
    for (int nt = 0; nt < 4; ++nt) {
      const int c = nt * 16 + m16;
      const float bb = sb1[c];
      #pragma unroll
      for (int r = 0; r < 4; ++r) {
        float x = acc[nt][r] + bb;             // C/D: row = quad*4+r, col = c
        float sv = x * __builtin_amdgcn_rcpf(1.f + __expf(-x));
        hw[(quad * 4 + r) * 72 + c] = (__bf16)sv;
      }
    }
    wave_lds_fence();  // per-wave buffer: no block barrier needed

    // ---- layer 2: [16 x 64] @ [64 x 64] ----
    f32x4 acc2[4] = {};
    #pragma unroll
    for (int ki = 0; ki < 2; ++ki) {
      bf16x8 a = *(const bf16x8*)&hw[m16 * 72 + ki * 32 + quad * 8];
      #pragma unroll
      for (int nt = 0; nt < 4; ++nt)
        acc2[nt] = __builtin_amdgcn_mfma_f32_16x16x32_bf16(a, w2f[ki][nt], acc2[nt], 0, 0, 0);
    }
    wave_lds_fence();  // WAR: next tile rewrites hbuf; keep order + no reg-caching

    // ---- epilogue: bias + SiLU + residual + LayerNorm (all fp32) ----
    #pragma unroll
    for (int r = 0; r < 4; ++r) {
      const int row = quad * 4 + r;
      const size_t eo = (size_t)(base + row) * D;
      float x[4];
      float sum = 0.f;
      #pragma unroll
      for (int nt = 0; nt < 4; ++nt) {
        const int c = nt * 16 + m16;
        float h = acc2[nt][r] + sb2[c];
        h = h * __builtin_amdgcn_rcpf(1.f + __expf(-h));
        x[nt] = ef[eo + c] + h;
        sum += x[nt];
      }
      float sq = x[0] * x[0] + x[1] * x[1] + x[2] * x[2] + x[3] * x[3];
      // row lives in one quad (16 consecutive lanes): xor masks 1,2,4,8
      #pragma unroll
      for (int off = 1; off < 16; off <<= 1) {
        sum += __shfl_xor(sum, off);
        sq  += __shfl_xor(sq, off);
      }
      const float mean = sum * (1.f / 64.f);
      const float var  = sq * (1.f / 64.f) - mean * mean;
      const float rstd = rsqrtf(var + 1e-5f);
      #pragma unroll
      for (int nt = 0; nt < 4; ++nt) {
        const int c = nt * 16 + m16;
        out[eo + c] = (x[nt] - mean) * rstd * sg[c] + sbt[c];
      }
    }
  }
}

extern "C" void kernel_launch(void* const* d_in, const int* in_sizes, int n_in,
                              void* d_out, int out_size, void* d_ws, size_t ws_size,
                              hipStream_t stream) {
  const float* nodes = (const float*)d_in[0];
  const float* ef    = (const float*)d_in[1];
  const int*   srci  = (const int*)d_in[2];
  const int*   dsti  = (const int*)d_in[3];
  const float* W1    = (const float*)d_in[4];
  const float* b1    = (const float*)d_in[5];
  const float* W2    = (const float*)d_in[6];
  const float* b2    = (const float*)d_in[7];
  const float* gmm   = (const float*)d_in[8];
  const float* bta   = (const float*)d_in[9];
  float* out = (float*)d_out;

  const int blocks = NE / 256;  // 3125, exact
  if (ws_size >= (size_t)(K1 * D + D * D) * 2) {
    prep_weights<<<64, 256, 0, stream>>>(W1, W2, (__bf16*)d_ws);
    edge_kernel<true><<<blocks, 256, 0, stream>>>(
        nodes, ef, srci, dsti, W1, b1, W2, b2, gmm, bta,
        (const __bf16*)d_ws, out);
  } else {
    edge_kernel<false><<<blocks, 256, 0, stream>>>(
        nodes, ef, srci, dsti, W1, b1, W2, b2, gmm, bta, nullptr, out);
  }
}

// Round 3
// 402.973 us; speedup vs baseline: 1.1689x; 1.1689x over previous
//
#include <hip/hip_runtime.h>

#define NE 800000
#define D  64
#define K1 192
#define AST 200  // A-tile / w1t row stride in bf16 (192 + 8 pad)

typedef __bf16 bf16x4v __attribute__((ext_vector_type(4)));
typedef __bf16 bf16x8  __attribute__((ext_vector_type(8)));
typedef float  f32x4   __attribute__((ext_vector_type(4)));

// Convert W1 (192x64, k-major) -> W1^T bf16 (64x192, n-major) at ws[0],
// and W2 (64x64) -> W2^T bf16 (64x64) at ws[12288]. 16384 threads total.
__global__ void prep_weights(const float* __restrict__ W1,
                             const float* __restrict__ W2,
                             __bf16* __restrict__ ws) {
  int i = blockIdx.x * 256 + threadIdx.x;
  if (i < K1 * D) {
    int k = i >> 6, n = i & 63;
    ws[n * K1 + k] = (__bf16)W1[i];
  } else {
    int j = i - K1 * D;
    int k = j >> 6, n = j & 63;
    ws[K1 * D + n * D + k] = (__bf16)W2[j];
  }
}

// Per-wave LDS ordering only (LDS pipe is in-order per wave); the asm memory
// clobber also stops the compiler from reordering LDS accesses across it.
__device__ __forceinline__ void wave_lds_fence() {
  __asm__ volatile("s_waitcnt lgkmcnt(0)" ::: "memory");
}

__device__ __forceinline__ float silu(float x) {
  return x * __builtin_amdgcn_rcpf(1.f + __expf(-x));
}

template <bool USE_WS>
__global__ __launch_bounds__(256, 3)
void edge_kernel(const float* __restrict__ nodes, const float* __restrict__ ef,
                 const int* __restrict__ srci, const int* __restrict__ dsti,
                 const float* __restrict__ W1, const float* __restrict__ b1,
                 const float* __restrict__ W2, const float* __restrict__ b2,
                 const float* __restrict__ gmm, const float* __restrict__ bta,
                 const __bf16* __restrict__ wsw, float* __restrict__ out) {
  // LDS: 25600 (w1t) + 4*6400 (A-tiles) + 1024 = 52224 B -> 3 blocks/CU.
  __shared__ __align__(16) __bf16 w1t[64 * AST];
  __shared__ __align__(16) __bf16 atile_all[4][16 * AST];
  __shared__ float sb1[64], sb2[64], sg[64], sbt[64];

  const int tid = threadIdx.x;
  const int wave = tid >> 6, lane = tid & 63;
  const int quad = lane >> 4, m16 = lane & 15;  // quad doubles as r4, m16 as c4

  if (USE_WS) {
    const uint2* s1 = (const uint2*)wsw;  // 3072 x 8B chunks of W1^T
    for (int c = tid; c < 3072; c += 256) {
      int n = c / 48, kc = c - n * 48;
      *(uint2*)&w1t[n * AST + kc * 4] = s1[c];
    }
  } else {
    for (int i = tid; i < K1 * D; i += 256) {
      int k = i >> 6, n = i & 63;
      w1t[n * AST + k] = (__bf16)W1[i];
    }
  }
  if (tid < 64)       sb1[tid]       = b1[tid];
  else if (tid < 128) sb2[tid - 64]  = b2[tid - 64];
  else if (tid < 192) sg[tid - 128]  = gmm[tid - 128];
  else                sbt[tid - 192] = bta[tid - 192];

  // W2^T B-fragments in registers (loop-invariant): 8 x bf16x8 = 32 VGPR.
  bf16x8 w2f[2][4];
  if (USE_WS) {
    const __bf16* w2t = wsw + K1 * D;  // 64x64, n-major
    #pragma unroll
    for (int ki = 0; ki < 2; ++ki)
      #pragma unroll
      for (int nt = 0; nt < 4; ++nt)
        w2f[ki][nt] = *(const bf16x8*)&w2t[(nt * 16 + m16) * 64 + ki * 32 + quad * 8];
  } else {
    #pragma unroll
    for (int ki = 0; ki < 2; ++ki)
      #pragma unroll
      for (int nt = 0; nt < 4; ++nt) {
        const int n = nt * 16 + m16;
        #pragma unroll
        for (int j = 0; j < 8; ++j)
          w2f[ki][nt][j] = (__bf16)W2[(ki * 32 + quad * 8 + j) * 64 + n];
      }
  }
  __syncthreads();  // w1t + bias staging visible to all waves

  __bf16* At = atile_all[wave];
  float*  Af = (float*)At;  // fp32 view for output staging (row stride 100 f32)

  #pragma unroll 1
  for (int t = 0; t < 4; ++t) {
    const int base = blockIdx.x * 256 + wave * 64 + t * 16;

    // ---- coalesced staging: 16 edges' concat rows -> A-tile (bf16) ----
    // lane = 16 lanes per row: row = i*4 + quad-group, 16B chunk = m16.
    int si[4], di[4];
    #pragma unroll
    for (int i = 0; i < 4; ++i) {
      si[i] = srci[base + i * 4 + quad];
      di[i] = dsti[base + i * 4 + quad];
    }
    #pragma unroll
    for (int i = 0; i < 4; ++i) {
      const int row = i * 4 + quad;
      f32x4 sv = *(const f32x4*)(nodes + (size_t)si[i] * D + m16 * 4);
      f32x4 dv = *(const f32x4*)(nodes + (size_t)di[i] * D + m16 * 4);
      f32x4 ev = *(const f32x4*)(ef + (size_t)(base + row) * D + m16 * 4);
      bf16x4v sb, db, eb;
      #pragma unroll
      for (int j = 0; j < 4; ++j) {
        sb[j] = (__bf16)sv[j]; db[j] = (__bf16)dv[j]; eb[j] = (__bf16)ev[j];
      }
      *(bf16x4v*)&At[row * AST +       m16 * 4] = sb;
      *(bf16x4v*)&At[row * AST +  64 + m16 * 4] = db;
      *(bf16x4v*)&At[row * AST + 128 + m16 * 4] = eb;
    }
    wave_lds_fence();

    // ---- layer 1: [16 x 192] @ [192 x 64] ----
    f32x4 acc[4] = {};
    #pragma unroll
    for (int ki = 0; ki < 6; ++ki) {
      bf16x8 a = *(const bf16x8*)&At[m16 * AST + ki * 32 + quad * 8];
      #pragma unroll
      for (int nt = 0; nt < 4; ++nt) {
        bf16x8 bfv = *(const bf16x8*)&w1t[(nt * 16 + m16) * AST + ki * 32 + quad * 8];
        acc[nt] = __builtin_amdgcn_mfma_f32_16x16x32_bf16(a, bfv, acc[nt], 0, 0, 0);
      }
    }

    // bias + SiLU; h1 -> A-tile cols 0..63 (src/dst slabs dead, ef preserved)
    #pragma unroll
    for (int nt = 0; nt < 4; ++nt) {
      const int c = nt * 16 + m16;
      const float bb = sb1[c];
      #pragma unroll
      for (int r = 0; r < 4; ++r)
        At[(quad * 4 + r) * AST + c] = (__bf16)silu(acc[nt][r] + bb);
    }
    wave_lds_fence();

    // ---- layer 2: [16 x 64] @ [64 x 64] ----
    f32x4 acc2[4] = {};
    #pragma unroll
    for (int ki = 0; ki < 2; ++ki) {
      bf16x8 a = *(const bf16x8*)&At[m16 * AST + ki * 32 + quad * 8];
      #pragma unroll
      for (int nt = 0; nt < 4; ++nt)
        acc2[nt] = __builtin_amdgcn_mfma_f32_16x16x32_bf16(a, w2f[ki][nt], acc2[nt], 0, 0, 0);
    }

    // ---- epilogue: bias + SiLU + residual(bf16 ef from LDS) + LayerNorm ----
    #pragma unroll
    for (int r = 0; r < 4; ++r) {
      const int row = quad * 4 + r;
      float x[4];
      float sum = 0.f;
      #pragma unroll
      for (int nt = 0; nt < 4; ++nt) {
        const int c = nt * 16 + m16;
        float h = silu(acc2[nt][r] + sb2[c]);
        float efv = (float)At[row * AST + 128 + c];
        x[nt] = efv + h;
        sum += x[nt];
      }
      float sq = x[0] * x[0] + x[1] * x[1] + x[2] * x[2] + x[3] * x[3];
      #pragma unroll
      for (int off = 1; off < 16; off <<= 1) {
        sum += __shfl_xor(sum, off);
        sq  += __shfl_xor(sq, off);
      }
      const float mean = sum * (1.f / 64.f);
      const float var  = sq * (1.f / 64.f) - mean * mean;
      const float rstd = rsqrtf(var + 1e-5f);
      // stage fp32 out rows in A-tile float view (cols 0..63; disjoint from
      // the bf16 ef slab at float cols 64..95)
      #pragma unroll
      for (int nt = 0; nt < 4; ++nt) {
        const int c = nt * 16 + m16;
        Af[row * (AST / 2) + c] = (x[nt] - mean) * rstd * sg[c] + sbt[c];
      }
    }
    wave_lds_fence();

    // ---- coalesced store: 4 dense 1-KB stores per wave ----
    #pragma unroll
    for (int i = 0; i < 4; ++i) {
      const int row = i * 4 + quad;
      f32x4 ov = *(const f32x4*)&Af[row * (AST / 2) + m16 * 4];
      *(f32x4*)(out + (size_t)(base + row) * D + m16 * 4) = ov;
    }
    wave_lds_fence();  // WAR: next t's staging rewrites the A-tile
  }
}

extern "C" void kernel_launch(void* const* d_in, const int* in_sizes, int n_in,
                              void* d_out, int out_size, void* d_ws, size_t ws_size,
                              hipStream_t stream) {
  const float* nodes = (const float*)d_in[0];
  const float* ef    = (const float*)d_in[1];
  const int*   srci  = (const int*)d_in[2];
  const int*   dsti  = (const int*)d_in[3];
  const float* W1    = (const float*)d_in[4];
  const float* b1    = (const float*)d_in[5];
  const float* W2    = (const float*)d_in[6];
  const float* b2    = (const float*)d_in[7];
  const float* gmm   = (const float*)d_in[8];
  const float* bta   = (const float*)d_in[9];
  float* out = (float*)d_out;

  const int blocks = NE / 256;  // 3125, exact
  if (ws_size >= (size_t)(K1 * D + D * D) * 2) {
    prep_weights<<<64, 256, 0, stream>>>(W1, W2, (__bf16*)d_ws);
    edge_kernel<true><<<blocks, 256, 0, stream>>>(
        nodes, ef, srci, dsti, W1, b1, W2, b2, gmm, bta,
        (const __bf16*)d_ws, out);
  } else {
    edge_kernel<false><<<blocks, 256, 0, stream>>>(
        nodes, ef, srci, dsti, W1, b1, W2, b2, gmm, bta, nullptr, out);
  }
}